// Round 1
// baseline (471.546 us; speedup 1.0000x reference)
//
#include <hip/hip_runtime.h>

// 2-layer LSTM (HID=10), B=2048, T=1024 main + F=64 future steps.
//
// Round 8: producer/consumer wave split. Evidence: r6->r7 halved dot-VALU for
// -2.4% wall, readlane<->bpermute swap neutral -> NOT issue-bound; we are
// dependency-latency-bound at 2 waves/SIMD (occupancy 19.7%, wall ~890
// cyc/step vs ~360 cyc of issue work). Cell1 (h1,c1) never reads cell2 state,
// so split each element across 2 waves of a 128-thread block:
//   wave0: cell1, writes h1(t) into a double-buffered LDS ring (16-step chunks)
//   wave1: cell2 + head, one chunk behind, reads h1 via uniform ds_read
//          (broadcast, conflict-free); runs the serial future loop at the end.
// One __syncthreads per 16-step chunk; 4096 waves -> 4 waves/SIMD. Per-step
// math sequenced identically to r7 (same prescaled constants), absmax ~6e-5.

#define NB 2048
#define TMAIN 1024
#define HID 10
#define KCH 16                  // steps per chunk
#define NCH (TMAIN / KCH)       // 64 chunks

typedef float v2f __attribute__((ext_vector_type(2)));

#define PIN2(v) asm volatile("" : "+v"(v))
#define PIN(v)  asm volatile("" : "+v"(v))

__device__ __forceinline__ float rcp_(float v)  { return __builtin_amdgcn_rcpf(v); }
__device__ __forceinline__ float exp2_(float v) { return __builtin_amdgcn_exp2f(v); }
__device__ __forceinline__ v2f mk2(float x, float y) { v2f r; r.x = x; r.y = y; return r; }
__device__ __forceinline__ v2f pfma(v2f a, v2f b, v2f c) { return __builtin_elementwise_fma(a, b, c); }

__global__ __launch_bounds__(128)
__attribute__((amdgpu_waves_per_eu(4)))
void lstm2_kernel(
    const float* __restrict__ x,
    const float* __restrict__ Wih1, const float* __restrict__ Whh1,
    const float* __restrict__ bih1, const float* __restrict__ bhh1,
    const float* __restrict__ Wih2, const float* __restrict__ Whh2,
    const float* __restrict__ bih2, const float* __restrict__ bhh2,
    const float* __restrict__ Wlin, const float* __restrict__ blin,
    const int* __restrict__ futp,
    float* __restrict__ out)
{
    const int tid  = threadIdx.x;
    const int wid  = tid >> 6;          // 0 = cell1 producer, 1 = cell2 consumer
    const int lane = tid & 63;
    const int ge   = blockIdx.x;
    const int F    = futp[0];
    const int OUTW = TMAIN + F;

    __shared__ float ring[2][KCH][16];  // h1(t) slots, 64B rows
    __shared__ float stfin[16];         // final c1 handoff for future loop

    const int L = (lane < 40) ? lane : 0;
    const int k = L / HID;
    const int u = L - k * HID;

    const bool isg = (k == 2);
    const float aK = isg ?  2.8853900817779268f : -1.4426950408889634f;
    const float tK = 2.8853900817779268f;
    // g-gate act pre-scaled by tK: cell states carry tK*c, so ctanh needs no mul
    const float aA = isg ?  tK         : 0.0f;
    const float aB = isg ? -2.0f * tK  : 1.0f;

    // ---- per-lane weights (row L), prescaled by aK, packed in v2f pairs ----
    v2f whh1p[5], wih2p[5], whh2p[5], wlinp[5];
    #pragma unroll
    for (int j = 0; j < 5; ++j) {
        whh1p[j] = mk2(Whh1[L * HID + 2*j] * aK, Whh1[L * HID + 2*j + 1] * aK);
        wih2p[j] = mk2(Wih2[L * HID + 2*j] * aK, Wih2[L * HID + 2*j + 1] * aK);
        whh2p[j] = mk2(Whh2[L * HID + 2*j] * aK, Whh2[L * HID + 2*j + 1] * aK);
        wlinp[j] = mk2(Wlin[2*j], Wlin[2*j + 1]);
    }
    float wih1v = Wih1[L] * aK;
    float b1 = (bih1[L] + bhh1[L]) * aK;
    float b2 = (bih2[L] + bhh2[L]) * aK;
    float bl = blin[0];

    #pragma unroll
    for (int j = 0; j < 5; ++j) { PIN2(whh1p[j]); PIN2(wih2p[j]); PIN2(whh2p[j]); PIN2(wlinp[j]); }
    PIN(wih1v); PIN(b1); PIN(b2); PIN(bl);

    const int adr_f = (1 * HID + u) * 4;
    const int adr_g = (2 * HID + u) * 4;
    const int adr_o = (3 * HID + u) * 4;

    auto bp = [](int addr, float v) -> float {
        return __int_as_float(__builtin_amdgcn_ds_bpermute(addr, __float_as_int(v)));
    };
    auto actf = [&](float p) -> float {          // sigma (or tK*tanh on g-lanes)
        return fmaf(aB, rcp_(1.0f + exp2_(p)), aA);
    };
    auto ctanh = [&](float cs) -> float {        // tanh of (pre-scaled) cell state
        return fmaf(-2.0f, rcp_(1.0f + exp2_(cs)), 1.0f);
    };

    // ---- state ----
    float c1 = 0.f, c2 = 0.f;
    v2f h1p[5], h2p[5];
    #pragma unroll
    for (int j = 0; j < 5; ++j) { h1p[j] = mk2(0.f, 0.f); h2p[j] = mk2(0.f, 0.f); }

    auto bcast1 = [&](float h1u) {
        #pragma unroll
        for (int j = 0; j < 5; ++j) { h1p[j].x = bp(8*j, h1u); h1p[j].y = bp(8*j + 4, h1u); }
    };
    auto bcast2 = [&](float h2u) {
        #pragma unroll
        for (int j = 0; j < 5; ++j) { h2p[j].x = bp(8*j, h2u); h2p[j].y = bp(8*j + 4, h2u); }
    };
    auto head = [&]() -> float {
        v2f Y = pfma(h2p[0], wlinp[0], mk2(bl, 0.f));
        #pragma unroll
        for (int j = 1; j < 5; ++j) Y = pfma(h2p[j], wlinp[j], Y);
        return Y.x + Y.y;
    };

    // cell1 step: consumes xt + h1p/c1, refreshes h1p/c1, returns h1u (lane u valid)
    auto cell1 = [&](float xt) -> float {
        v2f A = pfma(h1p[0], whh1p[0], mk2(fmaf(xt, wih1v, b1), 0.f));
        #pragma unroll
        for (int j = 1; j < 5; ++j) A = pfma(h1p[j], whh1p[j], A);
        float act1 = actf(A.x + A.y);
        float f1 = bp(adr_f, act1), g1 = bp(adr_g, act1), o1 = bp(adr_o, act1);
        c1 = fmaf(f1, c1, act1 * g1);
        float h1u = o1 * ctanh(c1);
        bcast1(h1u);
        return h1u;
    };

    // cell2 step: consumes h1p (input stream) + h2p/c2, returns y
    auto cell2 = [&]() -> float {
        v2f U = pfma(h1p[0], wih2p[0], mk2(b2, 0.f));
        v2f V = h2p[0] * whh2p[0];
        #pragma unroll
        for (int j = 1; j < 5; ++j) {
            U = pfma(h1p[j], wih2p[j], U);
            V = pfma(h2p[j], whh2p[j], V);
        }
        float act2 = actf((U.x + U.y) + (V.x + V.y));
        float f2 = bp(adr_f, act2), g2 = bp(adr_g, act2), o2 = bp(adr_o, act2);
        c2 = fmaf(f2, c2, act2 * g2);
        float h2u = o2 * ctanh(c2);
        bcast2(h2u);
        return head();
    };

    auto fstep = [&](float xt) -> float {        // serial future step (wave1)
        cell1(xt);
        return cell2();
    };

    const float4* xrow = (const float4*)(x + (size_t)ge * TMAIN);
    float4* orow = (float4*)(out + (size_t)ge * OUTW);   // OUTW=1088, 16B-aligned rows

    // ---- main pipeline: 65 chunk-iterations, consumer one chunk behind ----
    #pragma unroll 1
    for (int c = 0; c <= NCH; ++c) {
        if (wid == 0) {
            if (c < NCH) {
                float* reg = &ring[c & 1][0][0];
                #pragma unroll 1
                for (int q = 0; q < KCH / 4; ++q) {
                    float4 xv = xrow[c * (KCH / 4) + q];
                    float ha = cell1(xv.x);
                    float hb = cell1(xv.y);
                    float hc = cell1(xv.z);
                    float hd = cell1(xv.w);
                    if (lane < HID) {
                        reg[(q * 4 + 0) * 16 + lane] = ha;
                        reg[(q * 4 + 1) * 16 + lane] = hb;
                        reg[(q * 4 + 2) * 16 + lane] = hc;
                        reg[(q * 4 + 3) * 16 + lane] = hd;
                    }
                }
                if (c == NCH - 1 && lane < HID) stfin[lane] = c1;  // final c1 handoff
            }
        } else {
            if (c >= 1) {
                const float* reg = &ring[(c - 1) & 1][0][0];
                #pragma unroll 1
                for (int q = 0; q < KCH / 4; ++q) {
                    float yv[4];
                    #pragma unroll
                    for (int s = 0; s < 4; ++s) {
                        const v2f* hp = (const v2f*)(reg + (q * 4 + s) * 16);
                        #pragma unroll
                        for (int j = 0; j < 5; ++j) h1p[j] = hp[j];  // uniform-addr bcast reads
                        yv[s] = cell2();
                    }
                    if (lane == 0)
                        orow[(c - 1) * (KCH / 4) + q] = make_float4(yv[0], yv[1], yv[2], yv[3]);
                }
            }
        }
        __syncthreads();
    }

    // ---- future loop: wave1 only, fully serial (y feeds back) ----
    if (wid == 1) {
        c1 = stfin[u];            // h1p already holds h1(T-1) from last consume
        float yprev = head();
        int t = 0;
        #pragma unroll 1
        for (; t + 3 < F; t += 4) {
            float y0 = fstep(yprev);
            float y1 = fstep(y0);
            float y2 = fstep(y1);
            float y3 = fstep(y2);
            if (lane == 0) orow[(TMAIN + t) / 4] = make_float4(y0, y1, y2, y3);
            yprev = y3;
        }
        #pragma unroll 1
        for (; t < F; ++t) {
            yprev = fstep(yprev);
            if (lane == 0) out[(size_t)ge * OUTW + TMAIN + t] = yprev;
        }
    }
}

extern "C" void kernel_launch(void* const* d_in, const int* in_sizes, int n_in,
                              void* d_out, int out_size, void* d_ws, size_t ws_size,
                              hipStream_t stream) {
    const float* x    = (const float*)d_in[0];
    const float* Wih1 = (const float*)d_in[1];
    const float* Whh1 = (const float*)d_in[2];
    const float* bih1 = (const float*)d_in[3];
    const float* bhh1 = (const float*)d_in[4];
    const float* Wih2 = (const float*)d_in[5];
    const float* Whh2 = (const float*)d_in[6];
    const float* bih2 = (const float*)d_in[7];
    const float* bhh2 = (const float*)d_in[8];
    const float* Wlin = (const float*)d_in[9];
    const float* blin = (const float*)d_in[10];
    const int*   futp = (const int*)d_in[11];
    float* out = (float*)d_out;

    lstm2_kernel<<<NB, 128, 0, stream>>>(x, Wih1, Whh1, bih1, bhh1,
                                         Wih2, Whh2, bih2, bhh2,
                                         Wlin, blin, futp, out);
}